// Round 8
// baseline (97.266 us; speedup 1.0000x reference)
//
#include <hip/hip_runtime.h>
#include <hip/hip_bf16.h>

#define DD 256
#define SS 4096

typedef __bf16 bf16x8 __attribute__((ext_vector_type(8)));
typedef float  f32x4  __attribute__((ext_vector_type(4)));

__device__ __forceinline__ float fast_tanh(float x) {
  // tanh(x) = 1 - 2/(exp2(x*2*log2e)+1)
  float e = exp2f(x * 2.885390081777927f);
  return 1.0f - 2.0f / (e + 1.0f);
}

// DPP helpers: reduce across the 16-lane row (lg = lane&15) within each g-group
template<int CTRL>
__device__ __forceinline__ float dpp_mov(float v) {
  return __int_as_float(__builtin_amdgcn_update_dpp(0, __float_as_int(v), CTRL, 0xF, 0xF, true));
}
__device__ __forceinline__ float row16_sum(float v) {
  v += dpp_mov<0xB1>(v);   // quad_perm xor1
  v += dpp_mov<0x4E>(v);   // quad_perm xor2
  v += dpp_mov<0x124>(v);  // row_ror:4
  v += dpp_mov<0x128>(v);  // row_ror:8
  return v;
}
__device__ __forceinline__ float row16_max(float v) {
  v = fmaxf(v, dpp_mov<0xB1>(v));
  v = fmaxf(v, dpp_mov<0x4E>(v));
  v = fmaxf(v, dpp_mov<0x124>(v));
  v = fmaxf(v, dpp_mov<0x128>(v));
  return v;
}

// Prep: W [256,256] fp32 -> fragment-ordered bf16 WF (in d_ws).
// Chunk c = ((n0*8+ks)*64 + lane) holds 8 bf16: W[ks*32+(lane>>4)*8+i][n0*16+(lane&15)]
__global__ __launch_bounds__(256) void prep_kernel(
    const float* __restrict__ W, __bf16* __restrict__ WF)
{
  const int c = blockIdx.x * 256 + threadIdx.x;   // 8192 chunks
  const int lane_c = c & 63;
  const int ks  = (c >> 6) & 7;
  const int n0  = c >> 9;
  const int col = n0 * 16 + (lane_c & 15);
  const int k0  = ks * 32 + (lane_c >> 4) * 8;
  const float* wp = W + k0 * DD + col;
  bf16x8 fr;
  #pragma unroll
  for (int i = 0; i < 8; ++i) fr[i] = (__bf16)wp[i * DD];
  *reinterpret_cast<bf16x8*>(WF + (size_t)c * 8) = fr;
}

// Fused kernel: 256 blocks x 512 thr (8 waves), 1 block/CU (128 KB W in LDS).
// Each wave processes 4 chunks of 16 rows, software-pipelined: raw float4
// loads of chunk c+1 are issued before computing chunk c, so the X HBM
// stream overlaps MFMA/VALU continuously. Per (wave,chunk): logits (MFMA),
// strip softmax (m, se), weighted partial P[256] -> global. Combine kernel
// merges 256 partials per batch with max-rescale.
__global__ __launch_bounds__(512, 2) void fused_kernel(
    const float* __restrict__ X, const __bf16* __restrict__ WF,
    const float* __restrict__ bias, const float* __restrict__ V,
    float* __restrict__ Pout, float* __restrict__ Mout, float* __restrict__ Sout)
{
  __shared__ __bf16 WtF[8192 * 8];   // 128 KB, fragment-ordered (16B chunk per lane)
  __shared__ float  Vs[DD];
  __shared__ float  Bs[DD];

  const int t = threadIdx.x;
  const int wave = t >> 6, lane = t & 63;
  const int g  = lane >> 4;    // k-group 0..3 (DPP row)
  const int lg = lane & 15;    // sub-lane 0..15 (= row within strip)
  const size_t blockRow = (size_t)blockIdx.x * 512;

  // ---- Issue chunk-0 X loads FIRST (prime the HBM pipe before staging) ----
  float4 raw[16];
  {
    const float* xr = X + (blockRow + wave * 16 + lg) * DD;
    #pragma unroll
    for (int ks = 0; ks < 8; ++ks) {
      const float4* p = reinterpret_cast<const float4*>(xr + ks * 32 + g * 8);
      raw[2 * ks]     = p[0];
      raw[2 * ks + 1] = p[1];
    }
  }

  // ---- Stage W -> LDS (coalesced copy of prep output), V/bias ----
  {
    const uint4* src = reinterpret_cast<const uint4*>(WF);
    uint4* dst = reinterpret_cast<uint4*>(WtF);
    #pragma unroll
    for (int i = 0; i < 16; ++i) dst[t + i * 512] = src[t + i * 512];
  }
  if (t < DD) { Vs[t] = V[t]; Bs[t] = bias[t]; }
  __syncthreads();

  // ---- Chunk loop: 4 chunks x 16 rows per wave, 1-deep prefetch ----
  for (int c = 0; c < 4; ++c) {
    // Convert raw -> A fragments (lane: row lg, k = ks*32+g*8+i)
    bf16x8 a[8];
    #pragma unroll
    for (int ks = 0; ks < 8; ++ks) {
      float4 f0 = raw[2 * ks], f1 = raw[2 * ks + 1];
      bf16x8 fr;
      fr[0] = (__bf16)f0.x; fr[1] = (__bf16)f0.y; fr[2] = (__bf16)f0.z; fr[3] = (__bf16)f0.w;
      fr[4] = (__bf16)f1.x; fr[5] = (__bf16)f1.y; fr[6] = (__bf16)f1.z; fr[7] = (__bf16)f1.w;
      a[ks] = fr;
    }
    // Prefetch next chunk's raw X (overlaps with the tile loop below)
    if (c < 3) {
      const float* xr = X + (blockRow + (c + 1) * 128 + wave * 16 + lg) * DD;
      #pragma unroll
      for (int ks = 0; ks < 8; ++ks) {
        const float4* p = reinterpret_cast<const float4*>(xr + ks * 32 + g * 8);
        raw[2 * ks]     = p[0];
        raw[2 * ks + 1] = p[1];
      }
    }

    // ---- 16 col-tiles: 8 ds_read_b128 + 8 MFMA + tanh*V epilogue each ----
    float sp[4] = {0.f, 0.f, 0.f, 0.f};
    #pragma unroll 1
    for (int n0 = 0; n0 < 16; ++n0) {
      const __bf16* bp = WtF + ((size_t)(n0 * 8 * 64 + lane)) * 8;
      bf16x8 bfr[8];
      #pragma unroll
      for (int ks = 0; ks < 8; ++ks)
        bfr[ks] = *reinterpret_cast<const bf16x8*>(bp + (size_t)ks * 512);
      f32x4 acc = {0.f, 0.f, 0.f, 0.f};
      #pragma unroll
      for (int ks = 0; ks < 8; ++ks)
        acc = __builtin_amdgcn_mfma_f32_16x16x32_bf16(a[ks], bfr[ks], acc, 0, 0, 0);
      const int col = n0 * 16 + lg;
      const float vc = Vs[col], bc = Bs[col];
      #pragma unroll
      for (int r = 0; r < 4; ++r)            // C/D: col=lane&15, row=g*4+r
        sp[r] += fast_tanh(acc[r] + bc) * vc;
    }

    // Reduce logit partials across the 16 lg-lanes (DPP)
    #pragma unroll
    for (int r = 0; r < 4; ++r) sp[r] = row16_sum(sp[r]);

    // Redistribute: lane (g,lg) needs row lg -> src group lg>>2, reg lg&3
    const int src = ((lg >> 2) << 4) | lg;
    float l0 = 0.f;
    #pragma unroll
    for (int r = 0; r < 4; ++r) {
      float v0 = __shfl(sp[r], src, 64);
      if ((lg & 3) == r) l0 = v0;
    }

    // Strip softmax numerators
    const float m  = row16_max(l0);
    const float w0 = __expf(l0 - m);
    const float se = row16_sum(w0);

    // Weighted partial P[256] -> global (p8[i] covers d = ks*32+g*8+i)
    const int pid = blockIdx.x * 32 + c * 8 + wave;
    float* Pw = Pout + (size_t)pid * DD;
    #pragma unroll
    for (int ks = 0; ks < 8; ++ks) {
      float p8[8];
      #pragma unroll
      for (int i = 0; i < 8; ++i) p8[i] = w0 * (float)a[ks][i];
      #pragma unroll
      for (int i = 0; i < 8; ++i) p8[i] = row16_sum(p8[i]);
      if (lg < 2) {
        float4 v = (lg == 0) ? make_float4(p8[0], p8[1], p8[2], p8[3])
                             : make_float4(p8[4], p8[5], p8[6], p8[7]);
        *reinterpret_cast<float4*>(&Pw[ks * 32 + g * 8 + lg * 4]) = v;
      }
    }
    if (lane == 0) { Mout[pid] = m; Sout[pid] = se; }
  }
}

// Combine: per batch, merge the 256 partials with max-rescale.
__global__ __launch_bounds__(256) void combine_kernel(
    const float* __restrict__ P, const float* __restrict__ Mb,
    const float* __restrict__ Sb, float* __restrict__ ctx)
{
  const int b = blockIdx.x, t = threadIdx.x;
  const float* Mp = Mb + b * 256;
  const float* Sp = Sb + b * 256;
  float Mg = -1e30f;
  #pragma unroll 8
  for (int k = 0; k < 256; ++k) Mg = fmaxf(Mg, Mp[k]);
  float den = 0.f, acc = 0.f;
  #pragma unroll 4
  for (int k = 0; k < 256; ++k) {
    const float f = __expf(Mp[k] - Mg);
    den += f * Sp[k];
    acc += f * P[(size_t)(b * 256 + k) * DD + t];
  }
  ctx[b * DD + t] = acc / den;
}

extern "C" void kernel_launch(void* const* d_in, const int* in_sizes, int n_in,
                              void* d_out, int out_size, void* d_ws, size_t ws_size,
                              hipStream_t stream) {
  const float* X    = (const float*)d_in[0];  // [32,4096,256] fp32
  const float* W    = (const float*)d_in[1];  // [256,256]
  const float* bias = (const float*)d_in[2];  // [256]
  const float* V    = (const float*)d_in[3];  // [256,1]
  float* ctx = (float*)d_out;                 // [32,256]

  __bf16* WF = (__bf16*)d_ws;                       // 128 KB, fragment-ordered
  float* P = (float*)((char*)d_ws + 128 * 1024);    // [8192,256] = 8 MB
  float* M = P + 8192 * DD;                         // [8192]
  float* S = M + 8192;                              // [8192]

  prep_kernel<<<32, 256, 0, stream>>>(W, WF);
  fused_kernel<<<256, 512, 0, stream>>>(X, WF, bias, V, P, M, S);
  combine_kernel<<<32, 256, 0, stream>>>(P, M, S, ctx);
}

// Round 9
// 60.042 us; speedup vs baseline: 1.6200x; 1.6200x over previous
//
#include <hip/hip_runtime.h>
#include <hip/hip_bf16.h>

#define DD 256
#define SS 4096

typedef __bf16 bf16x8 __attribute__((ext_vector_type(8)));
typedef float  f32x4  __attribute__((ext_vector_type(4)));

__device__ __forceinline__ float fast_tanh(float x) {
  float e = exp2f(x * 2.885390081777927f);   // exp(2x)
  return 1.0f - 2.0f / (e + 1.0f);
}

// DPP helpers: reduce across the 16-lane row (lg = lane&15) within each g-group
template<int CTRL>
__device__ __forceinline__ float dpp_mov(float v) {
  return __int_as_float(__builtin_amdgcn_update_dpp(0, __float_as_int(v), CTRL, 0xF, 0xF, true));
}
__device__ __forceinline__ float row16_sum(float v) {
  v += dpp_mov<0xB1>(v);   // quad_perm xor1
  v += dpp_mov<0x4E>(v);   // quad_perm xor2
  v += dpp_mov<0x124>(v);  // row_ror:4
  v += dpp_mov<0x128>(v);  // row_ror:8
  return v;
}
__device__ __forceinline__ float row16_max(float v) {
  v = fmaxf(v, dpp_mov<0xB1>(v));
  v = fmaxf(v, dpp_mov<0x4E>(v));
  v = fmaxf(v, dpp_mov<0x124>(v));
  v = fmaxf(v, dpp_mov<0x128>(v));
  return v;
}

// Prep: W [256,256] fp32 -> fragment-ordered bf16 WF (in d_ws).
// Chunk c = ((n0*8+ks)*64 + lane) holds 8 bf16: W[ks*32+(lane>>4)*8+i][n0*16+(lane&15)]
__global__ __launch_bounds__(256) void prep_kernel(
    const float* __restrict__ W, __bf16* __restrict__ WF)
{
  const int c = blockIdx.x * 256 + threadIdx.x;   // 8192 chunks
  const int lane_c = c & 63;
  const int ks  = (c >> 6) & 7;
  const int n0  = c >> 9;
  const int col = n0 * 16 + (lane_c & 15);
  const int k0  = ks * 32 + (lane_c >> 4) * 8;
  const float* wp = W + k0 * DD + col;
  bf16x8 fr;
  #pragma unroll
  for (int i = 0; i < 8; ++i) fr[i] = (__bf16)wp[i * DD];
  *reinterpret_cast<bf16x8*>(WF + (size_t)c * 8) = fr;
}

#define PACK(dst, f0, f1) { \
  bf16x8 _fr; \
  _fr[0] = (__bf16)(f0).x; _fr[1] = (__bf16)(f0).y; \
  _fr[2] = (__bf16)(f0).z; _fr[3] = (__bf16)(f0).w; \
  _fr[4] = (__bf16)(f1).x; _fr[5] = (__bf16)(f1).y; \
  _fr[6] = (__bf16)(f1).z; _fr[7] = (__bf16)(f1).w; \
  (dst) = _fr; }

// One 16x16 output tile: 8 ds_read_b128 B-frags + 8 MFMA + tanh*V epilogue
#define TILE(aX, spX, n0q) { \
  const __bf16* _bp = WtF + ((size_t)((n0q) * 8 * 64 + lane)) * 8; \
  bf16x8 _bfr[8]; \
  _Pragma("unroll") \
  for (int _ks = 0; _ks < 8; ++_ks) \
    _bfr[_ks] = *reinterpret_cast<const bf16x8*>(_bp + (size_t)_ks * 512); \
  f32x4 _acc = {0.f, 0.f, 0.f, 0.f}; \
  _Pragma("unroll") \
  for (int _ks = 0; _ks < 8; ++_ks) \
    _acc = __builtin_amdgcn_mfma_f32_16x16x32_bf16(aX[_ks], _bfr[_ks], _acc, 0, 0, 0); \
  const int _col = (n0q) * 16 + lg; \
  const float _vc = Vs[_col], _bc = Bs[_col]; \
  _Pragma("unroll") \
  for (int _r = 0; _r < 4; ++_r) \
    spX[_r] += fast_tanh(_acc[_r] + _bc) * _vc; }

// Fused: 256 blocks x 1024 thr (16 waves/CU). Wave owns 32 rows as TWO
// 16-row strips, software-pipelined: strip-0 X loads primed at entry
// (before W staging); strip-1 loads issued in two halves under strip-0's
// tile pass. X read from HBM exactly once. Phase 3 (block softmax
// numerators) identical to the verified R4 kernel.
__global__ __launch_bounds__(1024, 1) __attribute__((amdgpu_waves_per_eu(4)))
void fused_kernel(
    const float* __restrict__ X, const __bf16* __restrict__ WF,
    const float* __restrict__ bias, const float* __restrict__ V,
    float* __restrict__ Pout, float* __restrict__ Mout, float* __restrict__ Sout)
{
  __shared__ __bf16 WtF[8192 * 8];    // 128 KB, fragment-ordered
  __shared__ float  Pacc[16][DD];     // 16 KB
  __shared__ float  Vs[DD];
  __shared__ float  Bs[DD];
  __shared__ float  wred[16];
  __shared__ float  sred[16];

  const int t = threadIdx.x;
  const int wave = t >> 6, lane = t & 63;
  const int g  = lane >> 4;    // k-group 0..3 (DPP row)
  const int lg = lane & 15;    // sub-lane 0..15 (= row within strip)
  const size_t rowBase = (size_t)blockIdx.x * 512 + (size_t)wave * 32;

  // ---- Prime strip-0 X loads FIRST (HBM starts at t=0) ----
  float4 raw[16];
  const float* xr0 = X + (rowBase + lg) * DD;
  #pragma unroll
  for (int ks = 0; ks < 8; ++ks) {
    const float4* p = reinterpret_cast<const float4*>(xr0 + ks * 32 + g * 8);
    raw[2 * ks]     = p[0];
    raw[2 * ks + 1] = p[1];
  }

  // ---- Stage W -> LDS (coalesced copy of prep output) ----
  {
    const uint4* src = reinterpret_cast<const uint4*>(WF);
    uint4* dst = reinterpret_cast<uint4*>(WtF);
    #pragma unroll
    for (int i = 0; i < 8; ++i) dst[t + i * 1024] = src[t + i * 1024];
  }
  if (t < DD) { Vs[t] = V[t]; Bs[t] = bias[t]; }
  __syncthreads();

  // ---- Convert strip 0; issue strip-1 first half ----
  bf16x8 a0[8], a1[8];
  #pragma unroll
  for (int ks = 0; ks < 8; ++ks) PACK(a0[ks], raw[2 * ks], raw[2 * ks + 1]);
  const float* xr1 = X + (rowBase + 16 + lg) * DD;
  #pragma unroll
  for (int ks = 0; ks < 4; ++ks) {
    const float4* p = reinterpret_cast<const float4*>(xr1 + ks * 32 + g * 8);
    raw[2 * ks]     = p[0];
    raw[2 * ks + 1] = p[1];
  }

  float sp0[4] = {0.f,0.f,0.f,0.f};
  float sp1[4] = {0.f,0.f,0.f,0.f};

  // ---- Strip-0 pass, tiles 0..7 (strip-1 first-half loads in flight) ----
  #pragma unroll 1
  for (int n0 = 0; n0 < 8; ++n0) TILE(a0, sp0, n0);

  // Convert strip-1 first half; issue second half
  #pragma unroll
  for (int ks = 0; ks < 4; ++ks) PACK(a1[ks], raw[2 * ks], raw[2 * ks + 1]);
  #pragma unroll
  for (int ks = 4; ks < 8; ++ks) {
    const float4* p = reinterpret_cast<const float4*>(xr1 + ks * 32 + g * 8);
    raw[2 * (ks - 4)]     = p[0];
    raw[2 * (ks - 4) + 1] = p[1];
  }

  // ---- Strip-0 pass, tiles 8..15 ----
  #pragma unroll 1
  for (int n0 = 8; n0 < 16; ++n0) TILE(a0, sp0, n0);

  // Convert strip-1 second half
  #pragma unroll
  for (int ks = 4; ks < 8; ++ks) PACK(a1[ks], raw[2 * (ks - 4)], raw[2 * (ks - 4) + 1]);

  // ---- Strip-1 pass, tiles 0..15 ----
  #pragma unroll 1
  for (int n0 = 0; n0 < 16; ++n0) TILE(a1, sp1, n0);

  // ---- Logit reduce across the 16 lg-lanes (DPP; all lanes get the sum) ----
  #pragma unroll
  for (int r = 0; r < 4; ++r) { sp0[r] = row16_sum(sp0[r]); sp1[r] = row16_sum(sp1[r]); }

  // Redistribute: lane (g,lg) needs rows lg / 16+lg -> src group lg>>2, reg lg&3
  const int src = ((lg >> 2) << 4) | lg;
  float l0 = 0.f, l1 = 0.f;
  #pragma unroll
  for (int r = 0; r < 4; ++r) {
    float v0 = __shfl(sp0[r], src, 64);
    float v1 = __shfl(sp1[r], src, 64);
    if ((lg & 3) == r) { l0 = v0; l1 = v1; }
  }

  // ---- Phase 3: block-local softmax numerators (identical to R4) ----
  float wm = row16_max(fmaxf(l0, l1));
  if (lane == 0) wred[wave] = wm;
  __syncthreads();
  float M = -1e30f;
  #pragma unroll
  for (int w = 0; w < 16; ++w) M = fmaxf(M, wred[w]);

  const float w0 = __expf(l0 - M);
  const float w1 = __expf(l1 - M);

  float se = row16_sum(w0 + w1);
  if (lane == 0) sred[wave] = se;

  #pragma unroll
  for (int ks = 0; ks < 8; ++ks) {
    float p8[8];
    #pragma unroll
    for (int i = 0; i < 8; ++i)
      p8[i] = w0 * (float)a0[ks][i] + w1 * (float)a1[ks][i];
    #pragma unroll
    for (int i = 0; i < 8; ++i) p8[i] = row16_sum(p8[i]);
    if (lg < 2) {
      float4 v = (lg == 0) ? make_float4(p8[0], p8[1], p8[2], p8[3])
                           : make_float4(p8[4], p8[5], p8[6], p8[7]);
      *reinterpret_cast<float4*>(&Pacc[wave][ks * 32 + g * 8 + lg * 4]) = v;
    }
  }
  __syncthreads();

  // ---- Phase 4: cross-wave reduce + write per-block partials ----
  if (t < DD) {
    float s = 0.f;
    #pragma unroll
    for (int w = 0; w < 16; ++w) s += Pacc[w][t];
    Pout[(size_t)blockIdx.x * DD + t] = s;
  }
  if (t == 0) {
    float ss = 0.f;
    #pragma unroll
    for (int w = 0; w < 16; ++w) ss += sred[w];
    Sout[blockIdx.x] = ss;
    Mout[blockIdx.x] = M;
  }
}

// Combine: per batch, merge the 8 block partials with max-rescale.
__global__ __launch_bounds__(256) void combine_kernel(
    const float* __restrict__ P, const float* __restrict__ Mb,
    const float* __restrict__ Sb, float* __restrict__ ctx)
{
  const int b = blockIdx.x, t = threadIdx.x;
  float Mg = -1e30f;
  #pragma unroll
  for (int k = 0; k < 8; ++k) Mg = fmaxf(Mg, Mb[b * 8 + k]);
  float denom = 0.f, acc = 0.f;
  #pragma unroll
  for (int k = 0; k < 8; ++k) {
    const float f = __expf(Mb[b * 8 + k] - Mg);
    denom += f * Sb[b * 8 + k];
    acc   += f * P[(size_t)(b * 8 + k) * DD + t];
  }
  ctx[b * DD + t] = acc / denom;
}

extern "C" void kernel_launch(void* const* d_in, const int* in_sizes, int n_in,
                              void* d_out, int out_size, void* d_ws, size_t ws_size,
                              hipStream_t stream) {
  const float* X    = (const float*)d_in[0];  // [32,4096,256] fp32
  const float* W    = (const float*)d_in[1];  // [256,256]
  const float* bias = (const float*)d_in[2];  // [256]
  const float* V    = (const float*)d_in[3];  // [256,1]
  float* ctx = (float*)d_out;                 // [32,256]

  __bf16* WF = (__bf16*)d_ws;                       // 128 KB, fragment-ordered
  float* P = (float*)((char*)d_ws + 128 * 1024);    // [256,256] = 256 KB
  float* M = P + 256 * DD;                          // [256]
  float* S = M + 256;                               // [256]

  prep_kernel<<<32, 256, 0, stream>>>(W, WF);
  fused_kernel<<<256, 1024, 0, stream>>>(X, WF, bias, V, P, M, S);
  combine_kernel<<<32, 256, 0, stream>>>(P, M, S, ctx);
}